// Round 1
// baseline (1086.798 us; speedup 1.0000x reference)
//
#include <hip/hip_runtime.h>

// 2-layer LSTM (B=512, T=300, D=80, H=128) + FC head, MFMA f16 persistent kernel.
// One WG per 16-batch tile; 8 waves; wave w owns hidden units [16w,16w+16).
// Weights held in registers as f16 MFMA B-fragments; h exchanged via swizzled LDS.

typedef _Float16 f16;
typedef _Float16 f16x8 __attribute__((ext_vector_type(8)));
typedef float f32x4 __attribute__((ext_vector_type(4)));

#define T_SEQ 300
#define D_IN  80
#define D_PAD 96
#define HDIM  128
#define B_ALL 512
#define B_TILE 16
#define N_WG  (B_ALL / B_TILE)   // 32

__device__ __forceinline__ float sigm(float x) {
    // 1/(1+2^(-x*log2e))
    return __builtin_amdgcn_rcpf(1.0f + __builtin_amdgcn_exp2f(-1.44269504f * x));
}
__device__ __forceinline__ float tanh_fast(float x) {
    // 1 - 2/(2^(2x*log2e)+1); saturates correctly at +-inf
    return 1.0f - 2.0f * __builtin_amdgcn_rcpf(1.0f + __builtin_amdgcn_exp2f(2.88539008f * x));
}

// ---------------- prep: x (B,D,T) f32 -> xT (B,T,D_PAD) f16, zero-padded d>=80
__global__ __launch_bounds__(256) void k_prep(const float* __restrict__ x,
                                              f16* __restrict__ xT) {
    __shared__ f16 tile[D_IN][T_SEQ + 8];
    const int b = blockIdx.x;
    const int tid = threadIdx.x;
    const float* xb = x + (size_t)b * D_IN * T_SEQ;
    for (int i = tid; i < D_IN * T_SEQ; i += 256) {
        int d = i / T_SEQ;
        int t = i - d * T_SEQ;
        tile[d][t] = (f16)xb[i];
    }
    __syncthreads();
    f16* outb = xT + (size_t)b * T_SEQ * D_PAD;
    for (int i = tid; i < T_SEQ * (D_PAD / 8); i += 256) {
        int t  = i / (D_PAD / 8);
        int dc = i - t * (D_PAD / 8);
        f16x8 v;
#pragma unroll
        for (int e = 0; e < 8; ++e) {
            int d = dc * 8 + e;
            v[e] = (d < D_IN) ? tile[d][t] : (f16)0.0f;
        }
        *(f16x8*)(outb + t * D_PAD + dc * 8) = v;
    }
}

// Build a B-fragment (gate row `row` of W, k-range [k0,k0+8), zero beyond kmax)
__device__ __forceinline__ f16x8 load_wfrag(const float* __restrict__ W,
                                            int row, int ld, int k0, int kmax) {
    f16x8 v;
#pragma unroll
    for (int e = 0; e < 8; ++e) {
        int k = k0 + e;
        v[e] = (k < kmax) ? (f16)W[row * ld + k] : (f16)0.0f;
    }
    return v;
}

__global__ __launch_bounds__(512) void k_lstm(
    const f16* __restrict__ xT, f16* __restrict__ h1ws,
    const float* __restrict__ Wih0, const float* __restrict__ Whh0,
    const float* __restrict__ bih0, const float* __restrict__ bhh0,
    const float* __restrict__ Wih1, const float* __restrict__ Whh1,
    const float* __restrict__ bih1, const float* __restrict__ bhh1,
    const float* __restrict__ fc1w, const float* __restrict__ fc1b,
    const float* __restrict__ fc2w, const float* __restrict__ fc2b,
    const float* __restrict__ fc3w, const float* __restrict__ fc3b,
    float* __restrict__ out)
{
    const int tid = threadIdx.x;
    const int wv  = tid >> 6;       // wave 0..7
    const int l   = tid & 63;
    const int l16 = l & 15;
    const int lg  = l >> 4;         // lane group 0..3
    const int wg  = blockIdx.x;
    const int u   = wv * 16 + l16;  // hidden unit owned by this lane (gate col side)

    __shared__ __align__(16) f16 hbuf[2][16 * HDIM];  // double-buffered h, swizzled
    __shared__ float h2buf[16][HDIM];
    __shared__ float a1buf[16][64];
    __shared__ float a2buf[16][33];

    for (int i = tid; i < 16 * HDIM; i += 512) hbuf[0][i] = (f16)0.0f;

    float cst[4] = {0.f, 0.f, 0.f, 0.f};
    float hlast[4] = {0.f, 0.f, 0.f, 0.f};

    // ================= layer 0 =================
    {
        f16x8 wih[4][3], whh[4][4];
        float biasv[4];
#pragma unroll
        for (int nt = 0; nt < 4; ++nt) {
            int gate = nt * 128 + u;
            biasv[nt] = bih0[gate] + bhh0[gate];
#pragma unroll
            for (int kc = 0; kc < 4; ++kc)
                whh[nt][kc] = load_wfrag(Whh0, gate, HDIM, kc * 32 + lg * 8, HDIM);
#pragma unroll
            for (int kc = 0; kc < 3; ++kc)
                wih[nt][kc] = load_wfrag(Wih0, gate, D_IN, kc * 32 + lg * 8, D_IN);
        }
        __syncthreads();  // hbuf[0] zeros visible

        const f16* xrow = xT + ((size_t)(wg * B_TILE + l16) * T_SEQ) * D_PAD + lg * 8;
        f16* h1base = h1ws + (size_t)(wg * B_TILE) * T_SEQ * HDIM;

        for (int t = 0; t < T_SEQ; ++t) {
            const f16* xp = xrow + t * D_PAD;
            f16x8 xa0 = *(const f16x8*)(xp);
            f16x8 xa1 = *(const f16x8*)(xp + 32);
            f16x8 xa2 = *(const f16x8*)(xp + 64);
            const f16* cur = hbuf[t & 1];
            f16* nxt = hbuf[(t + 1) & 1];
            f16x8 ha[4];
#pragma unroll
            for (int kc = 0; kc < 4; ++kc) {
                int chunk = kc * 4 + lg;
                ha[kc] = *(const f16x8*)(cur + l16 * HDIM + ((chunk ^ (l16 & 7)) << 3));
            }
            f32x4 acc[4];
#pragma unroll
            for (int nt = 0; nt < 4; ++nt) {
                f32x4 a = {biasv[nt], biasv[nt], biasv[nt], biasv[nt]};
                a = __builtin_amdgcn_mfma_f32_16x16x32_f16(xa0, wih[nt][0], a, 0, 0, 0);
                a = __builtin_amdgcn_mfma_f32_16x16x32_f16(xa1, wih[nt][1], a, 0, 0, 0);
                a = __builtin_amdgcn_mfma_f32_16x16x32_f16(xa2, wih[nt][2], a, 0, 0, 0);
                a = __builtin_amdgcn_mfma_f32_16x16x32_f16(ha[0], whh[nt][0], a, 0, 0, 0);
                a = __builtin_amdgcn_mfma_f32_16x16x32_f16(ha[1], whh[nt][1], a, 0, 0, 0);
                a = __builtin_amdgcn_mfma_f32_16x16x32_f16(ha[2], whh[nt][2], a, 0, 0, 0);
                a = __builtin_amdgcn_mfma_f32_16x16x32_f16(ha[3], whh[nt][3], a, 0, 0, 0);
                acc[nt] = a;
            }
#pragma unroll
            for (int r = 0; r < 4; ++r) {
                float iv = sigm(acc[0][r]);
                float fv = sigm(acc[1][r]);
                float gv = tanh_fast(acc[2][r]);
                float ov = sigm(acc[3][r]);
                float cn = fv * cst[r] + iv * gv;
                cst[r] = cn;
                float hv = ov * tanh_fast(cn);
                f16 hh = (f16)hv;
                int br = lg * 4 + r;  // batch row (C/D row mapping)
                nxt[br * HDIM + ((((unsigned)u >> 3) ^ (br & 7)) << 3) + (u & 7)] = hh;
                h1base[((size_t)br * T_SEQ + t) * HDIM + u] = hh;
            }
            __syncthreads();
        }
    }

    // ================= layer 1 =================
    {
        f16x8 wih[4][4], whh[4][4];
        float biasv[4];
#pragma unroll
        for (int nt = 0; nt < 4; ++nt) {
            int gate = nt * 128 + u;
            biasv[nt] = bih1[gate] + bhh1[gate];
#pragma unroll
            for (int kc = 0; kc < 4; ++kc) {
                wih[nt][kc] = load_wfrag(Wih1, gate, HDIM, kc * 32 + lg * 8, HDIM);
                whh[nt][kc] = load_wfrag(Whh1, gate, HDIM, kc * 32 + lg * 8, HDIM);
            }
        }
        for (int i = tid; i < 16 * HDIM; i += 512) hbuf[0][i] = (f16)0.0f;
#pragma unroll
        for (int r = 0; r < 4; ++r) cst[r] = 0.f;
        __syncthreads();

        const f16* h1row = h1ws + ((size_t)(wg * B_TILE + l16) * T_SEQ) * HDIM + lg * 8;

        for (int t = 0; t < T_SEQ; ++t) {
            const f16* xp = h1row + t * HDIM;
            f16x8 xa[4];
#pragma unroll
            for (int kc = 0; kc < 4; ++kc) xa[kc] = *(const f16x8*)(xp + kc * 32);
            const f16* cur = hbuf[t & 1];
            f16* nxt = hbuf[(t + 1) & 1];
            f16x8 ha[4];
#pragma unroll
            for (int kc = 0; kc < 4; ++kc) {
                int chunk = kc * 4 + lg;
                ha[kc] = *(const f16x8*)(cur + l16 * HDIM + ((chunk ^ (l16 & 7)) << 3));
            }
            f32x4 acc[4];
#pragma unroll
            for (int nt = 0; nt < 4; ++nt) {
                f32x4 a = {biasv[nt], biasv[nt], biasv[nt], biasv[nt]};
                a = __builtin_amdgcn_mfma_f32_16x16x32_f16(xa[0], wih[nt][0], a, 0, 0, 0);
                a = __builtin_amdgcn_mfma_f32_16x16x32_f16(xa[1], wih[nt][1], a, 0, 0, 0);
                a = __builtin_amdgcn_mfma_f32_16x16x32_f16(xa[2], wih[nt][2], a, 0, 0, 0);
                a = __builtin_amdgcn_mfma_f32_16x16x32_f16(xa[3], wih[nt][3], a, 0, 0, 0);
                a = __builtin_amdgcn_mfma_f32_16x16x32_f16(ha[0], whh[nt][0], a, 0, 0, 0);
                a = __builtin_amdgcn_mfma_f32_16x16x32_f16(ha[1], whh[nt][1], a, 0, 0, 0);
                a = __builtin_amdgcn_mfma_f32_16x16x32_f16(ha[2], whh[nt][2], a, 0, 0, 0);
                a = __builtin_amdgcn_mfma_f32_16x16x32_f16(ha[3], whh[nt][3], a, 0, 0, 0);
                acc[nt] = a;
            }
#pragma unroll
            for (int r = 0; r < 4; ++r) {
                float iv = sigm(acc[0][r]);
                float fv = sigm(acc[1][r]);
                float gv = tanh_fast(acc[2][r]);
                float ov = sigm(acc[3][r]);
                float cn = fv * cst[r] + iv * gv;
                cst[r] = cn;
                float hv = ov * tanh_fast(cn);
                hlast[r] = hv;
                int br = lg * 4 + r;
                nxt[br * HDIM + ((((unsigned)u >> 3) ^ (br & 7)) << 3) + (u & 7)] = (f16)hv;
            }
            __syncthreads();
        }
    }

    // ================= FC head on h2[:, T-1, :] =================
#pragma unroll
    for (int r = 0; r < 4; ++r) h2buf[lg * 4 + r][u] = hlast[r];
    __syncthreads();

    for (int i = tid; i < 16 * 64; i += 512) {
        int b = i >> 6, o = i & 63;
        float s = fc1b[o];
        for (int k = 0; k < HDIM; ++k) s += h2buf[b][k] * fc1w[o * HDIM + k];
        a1buf[b][o] = fmaxf(s, 0.f);
    }
    __syncthreads();
    if (tid < 16 * 32) {
        int b = tid >> 5, o = tid & 31;
        float s = fc2b[o];
        for (int k = 0; k < 64; ++k) s += a1buf[b][k] * fc2w[o * 64 + k];
        a2buf[b][o] = fmaxf(s, 0.f);
    }
    __syncthreads();
    if (tid < 32) {
        int b = tid >> 1, o = tid & 1;
        float s = fc3b[o];
        for (int k = 0; k < 32; ++k) s += a2buf[b][k] * fc3w[o * 32 + k];
        out[(wg * B_TILE + b) * 2 + o] = s;
    }
}

extern "C" void kernel_launch(void* const* d_in, const int* in_sizes, int n_in,
                              void* d_out, int out_size, void* d_ws, size_t ws_size,
                              hipStream_t stream)
{
    const float* x    = (const float*)d_in[0];
    const float* Wih0 = (const float*)d_in[1];
    const float* Whh0 = (const float*)d_in[2];
    const float* bih0 = (const float*)d_in[3];
    const float* bhh0 = (const float*)d_in[4];
    const float* Wih1 = (const float*)d_in[5];
    const float* Whh1 = (const float*)d_in[6];
    const float* bih1 = (const float*)d_in[7];
    const float* bhh1 = (const float*)d_in[8];
    const float* fc1w = (const float*)d_in[9];
    const float* fc1b = (const float*)d_in[10];
    const float* fc2w = (const float*)d_in[11];
    const float* fc2b = (const float*)d_in[12];
    const float* fc3w = (const float*)d_in[13];
    const float* fc3b = (const float*)d_in[14];

    f16* xT = (f16*)d_ws;                                           // 512*300*96*2  = 29.5 MB
    f16* h1 = (f16*)((char*)d_ws +
                     (size_t)B_ALL * T_SEQ * D_PAD * sizeof(f16));  // 512*300*128*2 = 39.3 MB

    k_prep<<<B_ALL, 256, 0, stream>>>(x, xT);
    k_lstm<<<N_WG, 512, 0, stream>>>(xT, h1, Wih0, Whh0, bih0, bhh0,
                                     Wih1, Whh1, bih1, bhh1,
                                     fc1w, fc1b, fc2w, fc2b, fc3w, fc3b,
                                     (float*)d_out);
}

// Round 2
// 672.094 us; speedup vs baseline: 1.6170x; 1.6170x over previous
//
#include <hip/hip_runtime.h>

// 2-layer LSTM (B=512, T=300, D=80, H=128) + FC head, MFMA f16 persistent kernel.
// One WG per 16-batch tile; 8 waves; wave w owns hidden units [16w,16w+16).
// Weights held in registers as f16 MFMA B-fragments; h exchanged via swizzled LDS.
// Round 2: no-vmcnt-drain barrier in recurrent loops + depth-1 global prefetch +
// h1 laid out [t][b][u] for contiguous streaming.

typedef _Float16 f16;
typedef _Float16 f16x8 __attribute__((ext_vector_type(8)));
typedef float f32x4 __attribute__((ext_vector_type(4)));

#define T_SEQ 300
#define D_IN  80
#define D_PAD 96
#define HDIM  128
#define B_ALL 512
#define B_TILE 16
#define N_WG  (B_ALL / B_TILE)   // 32

__device__ __forceinline__ float sigm(float x) {
    return __builtin_amdgcn_rcpf(1.0f + __builtin_amdgcn_exp2f(-1.44269504f * x));
}
__device__ __forceinline__ float tanh_fast(float x) {
    return 1.0f - 2.0f * __builtin_amdgcn_rcpf(1.0f + __builtin_amdgcn_exp2f(2.88539008f * x));
}

// Workgroup barrier that drains ONLY LDS (lgkmcnt); global loads/stores stay in
// flight across steps (avoids hipcc's vmcnt(0) drain before s_barrier).
__device__ __forceinline__ void wg_barrier_lds() {
    asm volatile("s_waitcnt lgkmcnt(0)" ::: "memory");
    __builtin_amdgcn_sched_barrier(0);
    __builtin_amdgcn_s_barrier();
    __builtin_amdgcn_sched_barrier(0);
}

// ---------------- prep: x (B,D,T) f32 -> xT (B,T,D_PAD) f16, zero-padded d>=80
__global__ __launch_bounds__(256) void k_prep(const float* __restrict__ x,
                                              f16* __restrict__ xT) {
    __shared__ f16 tile[D_IN][T_SEQ + 8];
    const int b = blockIdx.x;
    const int tid = threadIdx.x;
    const float* xb = x + (size_t)b * D_IN * T_SEQ;
    for (int i = tid; i < D_IN * T_SEQ; i += 256) {
        int d = i / T_SEQ;
        int t = i - d * T_SEQ;
        tile[d][t] = (f16)xb[i];
    }
    __syncthreads();
    f16* outb = xT + (size_t)b * T_SEQ * D_PAD;
    for (int i = tid; i < T_SEQ * (D_PAD / 8); i += 256) {
        int t  = i / (D_PAD / 8);
        int dc = i - t * (D_PAD / 8);
        f16x8 v;
#pragma unroll
        for (int e = 0; e < 8; ++e) {
            int d = dc * 8 + e;
            v[e] = (d < D_IN) ? tile[d][t] : (f16)0.0f;
        }
        *(f16x8*)(outb + t * D_PAD + dc * 8) = v;
    }
}

// Build a B-fragment (gate row `row` of W, k-range [k0,k0+8), zero beyond kmax)
__device__ __forceinline__ f16x8 load_wfrag(const float* __restrict__ W,
                                            int row, int ld, int k0, int kmax) {
    f16x8 v;
#pragma unroll
    for (int e = 0; e < 8; ++e) {
        int k = k0 + e;
        v[e] = (k < kmax) ? (f16)W[row * ld + k] : (f16)0.0f;
    }
    return v;
}

__global__ __launch_bounds__(512, 2) void k_lstm(
    const f16* __restrict__ xT, f16* __restrict__ h1ws,
    const float* __restrict__ Wih0, const float* __restrict__ Whh0,
    const float* __restrict__ bih0, const float* __restrict__ bhh0,
    const float* __restrict__ Wih1, const float* __restrict__ Whh1,
    const float* __restrict__ bih1, const float* __restrict__ bhh1,
    const float* __restrict__ fc1w, const float* __restrict__ fc1b,
    const float* __restrict__ fc2w, const float* __restrict__ fc2b,
    const float* __restrict__ fc3w, const float* __restrict__ fc3b,
    float* __restrict__ out)
{
    const int tid = threadIdx.x;
    const int wv  = tid >> 6;       // wave 0..7
    const int l   = tid & 63;
    const int l16 = l & 15;
    const int lg  = l >> 4;         // lane group 0..3
    const int wg  = blockIdx.x;
    const int u   = wv * 16 + l16;  // hidden unit owned by this lane (gate col side)

    __shared__ __align__(16) f16 hbuf[2][16 * HDIM];  // double-buffered h, swizzled
    __shared__ float h2buf[16][HDIM];
    __shared__ float a1buf[16][64];
    __shared__ float a2buf[16][33];

    for (int i = tid; i < 16 * HDIM; i += 512) hbuf[0][i] = (f16)0.0f;

    float cst[4] = {0.f, 0.f, 0.f, 0.f};
    float hlast[4] = {0.f, 0.f, 0.f, 0.f};

    // ================= layer 0 =================
    {
        f16x8 wih[4][3], whh[4][4];
        float biasv[4];
#pragma unroll
        for (int nt = 0; nt < 4; ++nt) {
            int gate = nt * 128 + u;
            biasv[nt] = bih0[gate] + bhh0[gate];
#pragma unroll
            for (int kc = 0; kc < 4; ++kc)
                whh[nt][kc] = load_wfrag(Whh0, gate, HDIM, kc * 32 + lg * 8, HDIM);
#pragma unroll
            for (int kc = 0; kc < 3; ++kc)
                wih[nt][kc] = load_wfrag(Wih0, gate, D_IN, kc * 32 + lg * 8, D_IN);
        }
        __syncthreads();  // hbuf[0] zeros visible

        const f16* xrow = xT + ((size_t)(wg * B_TILE + l16) * T_SEQ) * D_PAD + lg * 8;
        f16* h1base = h1ws;  // layout: [t][b][u]

        // preload x for t=0
        f16x8 xc0 = *(const f16x8*)(xrow);
        f16x8 xc1 = *(const f16x8*)(xrow + 32);
        f16x8 xc2 = *(const f16x8*)(xrow + 64);

        for (int t = 0; t < T_SEQ; ++t) {
            // prefetch x for t+1 (clamped); stays in flight across the barrier
            int tn = (t < T_SEQ - 1) ? t + 1 : t;
            const f16* xp = xrow + tn * D_PAD;
            f16x8 xn0 = *(const f16x8*)(xp);
            f16x8 xn1 = *(const f16x8*)(xp + 32);
            f16x8 xn2 = *(const f16x8*)(xp + 64);

            const f16* cur = hbuf[t & 1];
            f16* nxt = hbuf[(t + 1) & 1];
            f16x8 ha[4];
#pragma unroll
            for (int kc = 0; kc < 4; ++kc) {
                int chunk = kc * 4 + lg;
                ha[kc] = *(const f16x8*)(cur + l16 * HDIM + ((chunk ^ (l16 & 7)) << 3));
            }
            f32x4 acc[4];
#pragma unroll
            for (int nt = 0; nt < 4; ++nt) {
                f32x4 a = {biasv[nt], biasv[nt], biasv[nt], biasv[nt]};
                a = __builtin_amdgcn_mfma_f32_16x16x32_f16(xc0, wih[nt][0], a, 0, 0, 0);
                a = __builtin_amdgcn_mfma_f32_16x16x32_f16(xc1, wih[nt][1], a, 0, 0, 0);
                a = __builtin_amdgcn_mfma_f32_16x16x32_f16(xc2, wih[nt][2], a, 0, 0, 0);
                a = __builtin_amdgcn_mfma_f32_16x16x32_f16(ha[0], whh[nt][0], a, 0, 0, 0);
                a = __builtin_amdgcn_mfma_f32_16x16x32_f16(ha[1], whh[nt][1], a, 0, 0, 0);
                a = __builtin_amdgcn_mfma_f32_16x16x32_f16(ha[2], whh[nt][2], a, 0, 0, 0);
                a = __builtin_amdgcn_mfma_f32_16x16x32_f16(ha[3], whh[nt][3], a, 0, 0, 0);
                acc[nt] = a;
            }
#pragma unroll
            for (int r = 0; r < 4; ++r) {
                float iv = sigm(acc[0][r]);
                float fv = sigm(acc[1][r]);
                float gv = tanh_fast(acc[2][r]);
                float ov = sigm(acc[3][r]);
                float cn = fv * cst[r] + iv * gv;
                cst[r] = cn;
                float hv = ov * tanh_fast(cn);
                f16 hh = (f16)hv;
                int br = lg * 4 + r;  // batch row (C/D row mapping)
                nxt[br * HDIM + ((((unsigned)u >> 3) ^ (br & 7)) << 3) + (u & 7)] = hh;
                // h1 layout [t][b][u] -> contiguous row per (t,b), streams in t
                h1base[((size_t)t * B_ALL + wg * B_TILE + br) * HDIM + u] = hh;
            }
            xc0 = xn0; xc1 = xn1; xc2 = xn2;
            wg_barrier_lds();
        }
    }

    // phase boundary: h1 global stores must be visible before layer-1 loads
    asm volatile("s_waitcnt vmcnt(0) lgkmcnt(0)" ::: "memory");
    __syncthreads();

    // ================= layer 1 =================
    {
        f16x8 wih[4][4], whh[4][4];
        float biasv[4];
#pragma unroll
        for (int nt = 0; nt < 4; ++nt) {
            int gate = nt * 128 + u;
            biasv[nt] = bih1[gate] + bhh1[gate];
#pragma unroll
            for (int kc = 0; kc < 4; ++kc) {
                wih[nt][kc] = load_wfrag(Wih1, gate, HDIM, kc * 32 + lg * 8, HDIM);
                whh[nt][kc] = load_wfrag(Whh1, gate, HDIM, kc * 32 + lg * 8, HDIM);
            }
        }
        for (int i = tid; i < 16 * HDIM; i += 512) hbuf[0][i] = (f16)0.0f;
#pragma unroll
        for (int r = 0; r < 4; ++r) cst[r] = 0.f;
        __syncthreads();

        // h1 layout [t][b][u]; per-step stride = B_ALL*HDIM
        const f16* h1row = h1ws + ((size_t)(wg * B_TILE + l16)) * HDIM + lg * 8;
        const size_t tstride = (size_t)B_ALL * HDIM;

        // preload h1 input for t=0
        f16x8 xc[4];
#pragma unroll
        for (int kc = 0; kc < 4; ++kc) xc[kc] = *(const f16x8*)(h1row + kc * 32);

        for (int t = 0; t < T_SEQ; ++t) {
            // prefetch h1 for t+1
            int tn = (t < T_SEQ - 1) ? t + 1 : t;
            const f16* xp = h1row + (size_t)tn * tstride;
            f16x8 xn0 = *(const f16x8*)(xp);
            f16x8 xn1 = *(const f16x8*)(xp + 32);
            f16x8 xn2 = *(const f16x8*)(xp + 64);
            f16x8 xn3 = *(const f16x8*)(xp + 96);

            const f16* cur = hbuf[t & 1];
            f16* nxt = hbuf[(t + 1) & 1];
            f16x8 ha[4];
#pragma unroll
            for (int kc = 0; kc < 4; ++kc) {
                int chunk = kc * 4 + lg;
                ha[kc] = *(const f16x8*)(cur + l16 * HDIM + ((chunk ^ (l16 & 7)) << 3));
            }
            f32x4 acc[4];
#pragma unroll
            for (int nt = 0; nt < 4; ++nt) {
                f32x4 a = {biasv[nt], biasv[nt], biasv[nt], biasv[nt]};
                a = __builtin_amdgcn_mfma_f32_16x16x32_f16(xc[0], wih[nt][0], a, 0, 0, 0);
                a = __builtin_amdgcn_mfma_f32_16x16x32_f16(xc[1], wih[nt][1], a, 0, 0, 0);
                a = __builtin_amdgcn_mfma_f32_16x16x32_f16(xc[2], wih[nt][2], a, 0, 0, 0);
                a = __builtin_amdgcn_mfma_f32_16x16x32_f16(xc[3], wih[nt][3], a, 0, 0, 0);
                a = __builtin_amdgcn_mfma_f32_16x16x32_f16(ha[0], whh[nt][0], a, 0, 0, 0);
                a = __builtin_amdgcn_mfma_f32_16x16x32_f16(ha[1], whh[nt][1], a, 0, 0, 0);
                a = __builtin_amdgcn_mfma_f32_16x16x32_f16(ha[2], whh[nt][2], a, 0, 0, 0);
                a = __builtin_amdgcn_mfma_f32_16x16x32_f16(ha[3], whh[nt][3], a, 0, 0, 0);
                acc[nt] = a;
            }
#pragma unroll
            for (int r = 0; r < 4; ++r) {
                float iv = sigm(acc[0][r]);
                float fv = sigm(acc[1][r]);
                float gv = tanh_fast(acc[2][r]);
                float ov = sigm(acc[3][r]);
                float cn = fv * cst[r] + iv * gv;
                cst[r] = cn;
                float hv = ov * tanh_fast(cn);
                hlast[r] = hv;
                int br = lg * 4 + r;
                nxt[br * HDIM + ((((unsigned)u >> 3) ^ (br & 7)) << 3) + (u & 7)] = (f16)hv;
            }
            xc[0] = xn0; xc[1] = xn1; xc[2] = xn2; xc[3] = xn3;
            wg_barrier_lds();
        }
    }

    // ================= FC head on h2[:, T-1, :] =================
#pragma unroll
    for (int r = 0; r < 4; ++r) h2buf[lg * 4 + r][u] = hlast[r];
    __syncthreads();

    for (int i = tid; i < 16 * 64; i += 512) {
        int b = i >> 6, o = i & 63;
        float s = fc1b[o];
        for (int k = 0; k < HDIM; ++k) s += h2buf[b][k] * fc1w[o * HDIM + k];
        a1buf[b][o] = fmaxf(s, 0.f);
    }
    __syncthreads();
    if (tid < 16 * 32) {
        int b = tid >> 5, o = tid & 31;
        float s = fc2b[o];
        for (int k = 0; k < 64; ++k) s += a1buf[b][k] * fc2w[o * 64 + k];
        a2buf[b][o] = fmaxf(s, 0.f);
    }
    __syncthreads();
    if (tid < 32) {
        int b = tid >> 1, o = tid & 1;
        float s = fc3b[o];
        for (int k = 0; k < 32; ++k) s += a2buf[b][k] * fc3w[o * 32 + k];
        out[(wg * B_TILE + b) * 2 + o] = s;
    }
}

extern "C" void kernel_launch(void* const* d_in, const int* in_sizes, int n_in,
                              void* d_out, int out_size, void* d_ws, size_t ws_size,
                              hipStream_t stream)
{
    const float* x    = (const float*)d_in[0];
    const float* Wih0 = (const float*)d_in[1];
    const float* Whh0 = (const float*)d_in[2];
    const float* bih0 = (const float*)d_in[3];
    const float* bhh0 = (const float*)d_in[4];
    const float* Wih1 = (const float*)d_in[5];
    const float* Whh1 = (const float*)d_in[6];
    const float* bih1 = (const float*)d_in[7];
    const float* bhh1 = (const float*)d_in[8];
    const float* fc1w = (const float*)d_in[9];
    const float* fc1b = (const float*)d_in[10];
    const float* fc2w = (const float*)d_in[11];
    const float* fc2b = (const float*)d_in[12];
    const float* fc3w = (const float*)d_in[13];
    const float* fc3b = (const float*)d_in[14];

    f16* xT = (f16*)d_ws;                                           // 512*300*96*2  = 29.5 MB
    f16* h1 = (f16*)((char*)d_ws +
                     (size_t)B_ALL * T_SEQ * D_PAD * sizeof(f16));  // 300*512*128*2 = 39.3 MB

    k_prep<<<B_ALL, 256, 0, stream>>>(x, xT);
    k_lstm<<<N_WG, 512, 0, stream>>>(xT, h1, Wih0, Whh0, bih0, bhh0,
                                     Wih1, Whh1, bih1, bhh1,
                                     fc1w, fc1b, fc2w, fc2b, fc3w, fc3b,
                                     (float*)d_out);
}

// Round 3
// 473.303 us; speedup vs baseline: 2.2962x; 1.4200x over previous
//
#include <hip/hip_runtime.h>

// 2-layer LSTM (B=512, T=300, D=80, H=128) + FC head on MI355X.
// Round 3: producer/consumer layer pipeline across 64 WGs.
//   WG 0..31  = layer 0 for batch tile wg   (producer)
//   WG 32..63 = layer 1 + FC for tile wg-32 (consumer, lags 1 step)
// h1 handed off through LLC via sc0/sc1 bypass stores/loads + per-step flags
// (relaxed agent atomics). Producer never waits on consumer -> deadlock-free.

typedef _Float16 f16;
typedef _Float16 f16x8 __attribute__((ext_vector_type(8)));
typedef float f32x4 __attribute__((ext_vector_type(4)));

#define T_SEQ 300
#define D_IN  80
#define HDIM  128
#define B_ALL 512
#define B_TILE 16
#define N_PROD 32
#define N_WG_TOT 64

#define XT_BYTES  ((size_t)B_ALL * T_SEQ * D_IN * 2)   // 24,576,000
#define H1_BYTES  ((size_t)T_SEQ * B_ALL * HDIM * 2)   // 39,321,600
#define FLAGS_OFF (XT_BYTES + H1_BYTES)
#define FLAGS_BYTES ((size_t)N_PROD * T_SEQ * 4)       // 38,400
#define HSTEP_BYTES ((uint64_t)B_ALL * HDIM * 2)       // 131072

// LLC-coherent (bypass vL1/L2) 16B load with immediate offset.
#define LLC_LOAD(dst, addr, OFFSTR)                                        \
    asm volatile("global_load_dwordx4 %0, %1, off offset:" OFFSTR " sc0 sc1" \
                 : "=v"(dst) : "v"(addr) : "memory")
// LLC-coherent 2B store with immediate offset.
#define LLC_STORE_SHORT(addr, val, OFFSTR)                                 \
    asm volatile("global_store_short %0, %1, off offset:" OFFSTR " sc0 sc1" \
                 :: "v"(addr), "v"(val) : "memory")

__device__ __forceinline__ float sigm(float x) {
    return __builtin_amdgcn_rcpf(1.0f + __builtin_amdgcn_exp2f(-1.44269504f * x));
}
__device__ __forceinline__ float tanh_fast(float x) {
    return 1.0f - 2.0f * __builtin_amdgcn_rcpf(1.0f + __builtin_amdgcn_exp2f(2.88539008f * x));
}

__device__ __forceinline__ void wg_barrier_lds() {
    asm volatile("s_waitcnt lgkmcnt(0)" ::: "memory");
    __builtin_amdgcn_sched_barrier(0);
    __builtin_amdgcn_s_barrier();
    __builtin_amdgcn_sched_barrier(0);
}

__device__ __forceinline__ int flag_ld(const int* p) {
    return __hip_atomic_load(p, __ATOMIC_RELAXED, __HIP_MEMORY_SCOPE_AGENT);
}

// ---------------- prep: x (B,D,T) f32 -> xT (B,T,80) f16
__global__ __launch_bounds__(256) void k_prep(const float* __restrict__ x,
                                              f16* __restrict__ xT) {
    __shared__ f16 tile[D_IN][T_SEQ + 8];
    const int b = blockIdx.x;
    const int tid = threadIdx.x;
    const float* xb = x + (size_t)b * D_IN * T_SEQ;
    for (int i = tid; i < D_IN * T_SEQ; i += 256) {
        int d = i / T_SEQ;
        int t = i - d * T_SEQ;
        tile[d][t] = (f16)xb[i];
    }
    __syncthreads();
    f16* outb = xT + (size_t)b * T_SEQ * D_IN;
    for (int i = tid; i < T_SEQ * (D_IN / 8); i += 256) {
        int t  = i / (D_IN / 8);
        int dc = i - t * (D_IN / 8);
        f16x8 v;
#pragma unroll
        for (int e = 0; e < 8; ++e) v[e] = tile[dc * 8 + e][t];
        *(f16x8*)(outb + t * D_IN + dc * 8) = v;
    }
}

// Build a B-fragment (gate row `row` of W, k-range [k0,k0+8), zero beyond kmax)
__device__ __forceinline__ f16x8 load_wfrag(const float* __restrict__ W,
                                            int row, int ld, int k0, int kmax) {
    f16x8 v;
#pragma unroll
    for (int e = 0; e < 8; ++e) {
        int k = k0 + e;
        v[e] = (k < kmax) ? (f16)W[row * ld + k] : (f16)0.0f;
    }
    return v;
}

__global__ __launch_bounds__(512, 2) void k_lstm(
    const f16* __restrict__ xT, f16* __restrict__ h1ws, int* __restrict__ flags,
    const float* __restrict__ Wih0, const float* __restrict__ Whh0,
    const float* __restrict__ bih0, const float* __restrict__ bhh0,
    const float* __restrict__ Wih1, const float* __restrict__ Whh1,
    const float* __restrict__ bih1, const float* __restrict__ bhh1,
    const float* __restrict__ fc1w, const float* __restrict__ fc1b,
    const float* __restrict__ fc2w, const float* __restrict__ fc2b,
    const float* __restrict__ fc3w, const float* __restrict__ fc3b,
    float* __restrict__ out)
{
    const int tid = threadIdx.x;
    const int wv  = tid >> 6;
    const int l   = tid & 63;
    const int l16 = l & 15;
    const int lg  = l >> 4;
    const int wg  = blockIdx.x;
    const int u   = wv * 16 + l16;

    __shared__ __align__(16) f16 hbuf[2][16 * HDIM];
    __shared__ float h2buf[16][HDIM];
    __shared__ float a1buf[16][64];
    __shared__ float a2buf[16][33];

    for (int i = tid; i < 16 * HDIM; i += 512) hbuf[0][i] = (f16)0.0f;

    float cst[4] = {0.f, 0.f, 0.f, 0.f};

    if (wg < N_PROD) {
        // ===================== PRODUCER: layer 0 =====================
        const int wgb = wg;
        f16x8 wih[4][3], whh[4][4];
        float biasv[4];
#pragma unroll
        for (int nt = 0; nt < 4; ++nt) {
            int gate = nt * 128 + u;
            biasv[nt] = bih0[gate] + bhh0[gate];
#pragma unroll
            for (int kc = 0; kc < 4; ++kc)
                whh[nt][kc] = load_wfrag(Whh0, gate, HDIM, kc * 32 + lg * 8, HDIM);
#pragma unroll
            for (int kc = 0; kc < 3; ++kc)
                wih[nt][kc] = load_wfrag(Wih0, gate, D_IN, kc * 32 + lg * 8, D_IN);
        }
        __syncthreads();

        // x rows are 80 f16 = 160B; kc=2 reads k=64..95, lanes lg>=2 read
        // garbage beyond the row -- harmless, their weight k-rows are zero.
        const f16* xrow = xT + (size_t)(wgb * B_TILE + l16) * T_SEQ * D_IN + lg * 8;
        uint64_t haddr = (uint64_t)(uintptr_t)h1ws +
                         (((uint64_t)wgb * B_TILE + lg * 4) * HDIM + u) * 2;
        int* myflags = flags + wgb * T_SEQ;

        f16x8 xc0 = *(const f16x8*)(xrow);
        f16x8 xc1 = *(const f16x8*)(xrow + 32);
        f16x8 xc2 = *(const f16x8*)(xrow + 64);

        for (int t = 0; t < T_SEQ; ++t) {
            int tn = (t < T_SEQ - 1) ? t + 1 : t;
            const f16* xp = xrow + tn * D_IN;
            f16x8 xn0 = *(const f16x8*)(xp);
            f16x8 xn1 = *(const f16x8*)(xp + 32);
            f16x8 xn2 = *(const f16x8*)(xp + 64);

            const f16* cur = hbuf[t & 1];
            f16* nxt = hbuf[(t + 1) & 1];
            f16x8 ha[4];
#pragma unroll
            for (int kc = 0; kc < 4; ++kc) {
                int chunk = kc * 4 + lg;
                ha[kc] = *(const f16x8*)(cur + l16 * HDIM + ((chunk ^ (l16 & 7)) << 3));
            }
            f32x4 acc[4];
#pragma unroll
            for (int nt = 0; nt < 4; ++nt) {
                f32x4 a = {biasv[nt], biasv[nt], biasv[nt], biasv[nt]};
                a = __builtin_amdgcn_mfma_f32_16x16x32_f16(xc0, wih[nt][0], a, 0, 0, 0);
                a = __builtin_amdgcn_mfma_f32_16x16x32_f16(xc1, wih[nt][1], a, 0, 0, 0);
                a = __builtin_amdgcn_mfma_f32_16x16x32_f16(xc2, wih[nt][2], a, 0, 0, 0);
                a = __builtin_amdgcn_mfma_f32_16x16x32_f16(ha[0], whh[nt][0], a, 0, 0, 0);
                a = __builtin_amdgcn_mfma_f32_16x16x32_f16(ha[1], whh[nt][1], a, 0, 0, 0);
                a = __builtin_amdgcn_mfma_f32_16x16x32_f16(ha[2], whh[nt][2], a, 0, 0, 0);
                a = __builtin_amdgcn_mfma_f32_16x16x32_f16(ha[3], whh[nt][3], a, 0, 0, 0);
                acc[nt] = a;
            }
            unsigned hv[4];
#pragma unroll
            for (int r = 0; r < 4; ++r) {
                float iv = sigm(acc[0][r]);
                float fv = sigm(acc[1][r]);
                float gv = tanh_fast(acc[2][r]);
                float ov = sigm(acc[3][r]);
                float cn = fv * cst[r] + iv * gv;
                cst[r] = cn;
                f16 hh = (f16)(ov * tanh_fast(cn));
                int br = lg * 4 + r;
                nxt[br * HDIM + ((((unsigned)u >> 3) ^ (br & 7)) << 3) + (u & 7)] = hh;
                hv[r] = (unsigned)__builtin_bit_cast(unsigned short, hh);
            }
            // h1[t][b][u] handoff rows (br = lg*4 + 0..3, row stride 256B)
            LLC_STORE_SHORT(haddr, hv[0], "0");
            LLC_STORE_SHORT(haddr, hv[1], "256");
            LLC_STORE_SHORT(haddr, hv[2], "512");
            LLC_STORE_SHORT(haddr, hv[3], "768");
            haddr += HSTEP_BYTES;
            xc0 = xn0; xc1 = xn1; xc2 = xn2;

            // drain handoff stores (+prefetch loads), then publish flag[t]
            asm volatile("s_waitcnt vmcnt(0) lgkmcnt(0)" ::: "memory");
            __builtin_amdgcn_sched_barrier(0);
            __builtin_amdgcn_s_barrier();
            __builtin_amdgcn_sched_barrier(0);
            if (tid == 0)
                __hip_atomic_store(&myflags[t], 1, __ATOMIC_RELAXED,
                                   __HIP_MEMORY_SCOPE_AGENT);
        }
        return;  // producers done
    }

    // ===================== CONSUMER: layer 1 + FC =====================
    {
        const int wgb = wg - N_PROD;
        f16x8 wih[4][4], whh[4][4];
        float biasv[4];
#pragma unroll
        for (int nt = 0; nt < 4; ++nt) {
            int gate = nt * 128 + u;
            biasv[nt] = bih1[gate] + bhh1[gate];
#pragma unroll
            for (int kc = 0; kc < 4; ++kc) {
                wih[nt][kc] = load_wfrag(Wih1, gate, HDIM, kc * 32 + lg * 8, HDIM);
                whh[nt][kc] = load_wfrag(Whh1, gate, HDIM, kc * 32 + lg * 8, HDIM);
            }
        }
        __syncthreads();  // hbuf zeros visible

        int* myflags = flags + wgb * T_SEQ;
        // wait for h1[0]
        if (tid == 0) { while (flag_ld(&myflags[0]) == 0) {} }
        __syncthreads();

        uint64_t xaddr = (uint64_t)(uintptr_t)h1ws +
                         ((uint64_t)(wgb * B_TILE + l16) * HDIM) * 2 + lg * 16;
        f16x8 xn0, xn1, xn2, xn3;
        LLC_LOAD(xn0, xaddr, "0");
        LLC_LOAD(xn1, xaddr, "64");
        LLC_LOAD(xn2, xaddr, "128");
        LLC_LOAD(xn3, xaddr, "192");

        float hlast[4] = {0.f, 0.f, 0.f, 0.f};

        for (int t = 0; t < T_SEQ; ++t) {
            asm volatile("s_waitcnt vmcnt(0)" ::: "memory");  // xn ready
            __builtin_amdgcn_sched_barrier(0);

            int probe = 1;
            if (t < T_SEQ - 1)
                probe = flag_ld(&myflags[t + 1]);  // latency hides under MFMA

            const f16* cur = hbuf[t & 1];
            f16* nxt = hbuf[(t + 1) & 1];
            f16x8 ha[4];
#pragma unroll
            for (int kc = 0; kc < 4; ++kc) {
                int chunk = kc * 4 + lg;
                ha[kc] = *(const f16x8*)(cur + l16 * HDIM + ((chunk ^ (l16 & 7)) << 3));
            }
            f32x4 acc[4];
#pragma unroll
            for (int nt = 0; nt < 4; ++nt) {
                f32x4 a = {biasv[nt], biasv[nt], biasv[nt], biasv[nt]};
                a = __builtin_amdgcn_mfma_f32_16x16x32_f16(xn0, wih[nt][0], a, 0, 0, 0);
                a = __builtin_amdgcn_mfma_f32_16x16x32_f16(xn1, wih[nt][1], a, 0, 0, 0);
                a = __builtin_amdgcn_mfma_f32_16x16x32_f16(xn2, wih[nt][2], a, 0, 0, 0);
                a = __builtin_amdgcn_mfma_f32_16x16x32_f16(xn3, wih[nt][3], a, 0, 0, 0);
                a = __builtin_amdgcn_mfma_f32_16x16x32_f16(ha[0], whh[nt][0], a, 0, 0, 0);
                a = __builtin_amdgcn_mfma_f32_16x16x32_f16(ha[1], whh[nt][1], a, 0, 0, 0);
                a = __builtin_amdgcn_mfma_f32_16x16x32_f16(ha[2], whh[nt][2], a, 0, 0, 0);
                a = __builtin_amdgcn_mfma_f32_16x16x32_f16(ha[3], whh[nt][3], a, 0, 0, 0);
                acc[nt] = a;
            }

            if (t < T_SEQ - 1) {
                if (!probe) { while (flag_ld(&myflags[t + 1]) == 0) {} }
                xaddr += HSTEP_BYTES;
                LLC_LOAD(xn0, xaddr, "0");
                LLC_LOAD(xn1, xaddr, "64");
                LLC_LOAD(xn2, xaddr, "128");
                LLC_LOAD(xn3, xaddr, "192");
            }

#pragma unroll
            for (int r = 0; r < 4; ++r) {
                float iv = sigm(acc[0][r]);
                float fv = sigm(acc[1][r]);
                float gv = tanh_fast(acc[2][r]);
                float ov = sigm(acc[3][r]);
                float cn = fv * cst[r] + iv * gv;
                cst[r] = cn;
                float hv = ov * tanh_fast(cn);
                hlast[r] = hv;
                int br = lg * 4 + r;
                nxt[br * HDIM + ((((unsigned)u >> 3) ^ (br & 7)) << 3) + (u & 7)] = (f16)hv;
            }
            wg_barrier_lds();
        }

        // ================= FC head on h2[:, T-1, :] =================
#pragma unroll
        for (int r = 0; r < 4; ++r) h2buf[lg * 4 + r][u] = hlast[r];
        __syncthreads();

        for (int i = tid; i < 16 * 64; i += 512) {
            int b = i >> 6, o = i & 63;
            float s = fc1b[o];
            for (int k = 0; k < HDIM; ++k) s += h2buf[b][k] * fc1w[o * HDIM + k];
            a1buf[b][o] = fmaxf(s, 0.f);
        }
        __syncthreads();
        if (tid < 16 * 32) {
            int b = tid >> 5, o = tid & 31;
            float s = fc2b[o];
            for (int k = 0; k < 64; ++k) s += a1buf[b][k] * fc2w[o * 64 + k];
            a2buf[b][o] = fmaxf(s, 0.f);
        }
        __syncthreads();
        if (tid < 32) {
            int b = tid >> 1, o = tid & 1;
            float s = fc3b[o];
            for (int k = 0; k < 32; ++k) s += a2buf[b][k] * fc3w[o * 32 + k];
            out[(wgb * B_TILE + b) * 2 + o] = s;
        }
    }
}

extern "C" void kernel_launch(void* const* d_in, const int* in_sizes, int n_in,
                              void* d_out, int out_size, void* d_ws, size_t ws_size,
                              hipStream_t stream)
{
    const float* x    = (const float*)d_in[0];
    const float* Wih0 = (const float*)d_in[1];
    const float* Whh0 = (const float*)d_in[2];
    const float* bih0 = (const float*)d_in[3];
    const float* bhh0 = (const float*)d_in[4];
    const float* Wih1 = (const float*)d_in[5];
    const float* Whh1 = (const float*)d_in[6];
    const float* bih1 = (const float*)d_in[7];
    const float* bhh1 = (const float*)d_in[8];
    const float* fc1w = (const float*)d_in[9];
    const float* fc1b = (const float*)d_in[10];
    const float* fc2w = (const float*)d_in[11];
    const float* fc2b = (const float*)d_in[12];
    const float* fc3w = (const float*)d_in[13];
    const float* fc3b = (const float*)d_in[14];

    f16* xT    = (f16*)d_ws;
    f16* h1    = (f16*)((char*)d_ws + XT_BYTES);
    int* flags = (int*)((char*)d_ws + FLAGS_OFF);

    // flags must be zero at the start of every launch (replays included)
    hipMemsetAsync(flags, 0, FLAGS_BYTES, stream);
    k_prep<<<B_ALL, 256, 0, stream>>>(x, xT);
    k_lstm<<<N_WG_TOT, 512, 0, stream>>>(xT, h1, flags, Wih0, Whh0, bih0, bhh0,
                                         Wih1, Whh1, bih1, bhh1,
                                         fc1w, fc1b, fc2w, fc2b, fc3w, fc3b,
                                         (float*)d_out);
}

// Round 4
// 472.181 us; speedup vs baseline: 2.3017x; 1.0024x over previous
//
#include <hip/hip_runtime.h>

// 2-layer LSTM (B=512, T=300, D=80, H=128) + FC head on MI355X.
// Round 3: producer/consumer layer pipeline across 64 WGs.
//   WG 0..31  = layer 0 for batch tile wg   (producer)
//   WG 32..63 = layer 1 + FC for tile wg-32 (consumer, lags 1 step)
// h1 handed off through LLC via sc0/sc1 bypass stores/loads + per-step flags
// (relaxed agent atomics). Producer never waits on consumer -> deadlock-free.

typedef _Float16 f16;
typedef _Float16 f16x8 __attribute__((ext_vector_type(8)));
typedef float f32x4 __attribute__((ext_vector_type(4)));

#define T_SEQ 300
#define D_IN  80
#define HDIM  128
#define B_ALL 512
#define B_TILE 16
#define N_PROD 32
#define N_WG_TOT 64

#define XT_BYTES  ((size_t)B_ALL * T_SEQ * D_IN * 2)   // 24,576,000
#define H1_BYTES  ((size_t)T_SEQ * B_ALL * HDIM * 2)   // 39,321,600
#define FLAGS_OFF (XT_BYTES + H1_BYTES)
#define FLAGS_BYTES ((size_t)N_PROD * T_SEQ * 4)       // 38,400
#define HSTEP_BYTES ((uint64_t)B_ALL * HDIM * 2)       // 131072

// LLC-coherent (bypass vL1/L2) 16B load with immediate offset.
#define LLC_LOAD(dst, addr, OFFSTR)                                        \
    asm volatile("global_load_dwordx4 %0, %1, off offset:" OFFSTR " sc0 sc1" \
                 : "=v"(dst) : "v"(addr) : "memory")
// LLC-coherent 2B store with immediate offset.
#define LLC_STORE_SHORT(addr, val, OFFSTR)                                 \
    asm volatile("global_store_short %0, %1, off offset:" OFFSTR " sc0 sc1" \
                 :: "v"(addr), "v"(val) : "memory")

__device__ __forceinline__ float sigm(float x) {
    return __builtin_amdgcn_rcpf(1.0f + __builtin_amdgcn_exp2f(-1.44269504f * x));
}
__device__ __forceinline__ float tanh_fast(float x) {
    return 1.0f - 2.0f * __builtin_amdgcn_rcpf(1.0f + __builtin_amdgcn_exp2f(2.88539008f * x));
}

__device__ __forceinline__ void wg_barrier_lds() {
    asm volatile("s_waitcnt lgkmcnt(0)" ::: "memory");
    __builtin_amdgcn_sched_barrier(0);
    __builtin_amdgcn_s_barrier();
    __builtin_amdgcn_sched_barrier(0);
}

__device__ __forceinline__ int flag_ld(const int* p) {
    return __hip_atomic_load(p, __ATOMIC_RELAXED, __HIP_MEMORY_SCOPE_AGENT);
}

// ---------------- prep: x (B,D,T) f32 -> xT (B,T,80) f16
__global__ __launch_bounds__(256) void k_prep(const float* __restrict__ x,
                                              f16* __restrict__ xT) {
    __shared__ f16 tile[D_IN][T_SEQ + 8];
    const int b = blockIdx.x;
    const int tid = threadIdx.x;
    const float* xb = x + (size_t)b * D_IN * T_SEQ;
    for (int i = tid; i < D_IN * T_SEQ; i += 256) {
        int d = i / T_SEQ;
        int t = i - d * T_SEQ;
        tile[d][t] = (f16)xb[i];
    }
    __syncthreads();
    f16* outb = xT + (size_t)b * T_SEQ * D_IN;
    for (int i = tid; i < T_SEQ * (D_IN / 8); i += 256) {
        int t  = i / (D_IN / 8);
        int dc = i - t * (D_IN / 8);
        f16x8 v;
#pragma unroll
        for (int e = 0; e < 8; ++e) v[e] = tile[dc * 8 + e][t];
        *(f16x8*)(outb + t * D_IN + dc * 8) = v;
    }
}

// Build a B-fragment (gate row `row` of W, k-range [k0,k0+8), zero beyond kmax)
__device__ __forceinline__ f16x8 load_wfrag(const float* __restrict__ W,
                                            int row, int ld, int k0, int kmax) {
    f16x8 v;
#pragma unroll
    for (int e = 0; e < 8; ++e) {
        int k = k0 + e;
        v[e] = (k < kmax) ? (f16)W[row * ld + k] : (f16)0.0f;
    }
    return v;
}

__global__ __launch_bounds__(512, 2) void k_lstm(
    const f16* __restrict__ xT, f16* __restrict__ h1ws, int* __restrict__ flags,
    const float* __restrict__ Wih0, const float* __restrict__ Whh0,
    const float* __restrict__ bih0, const float* __restrict__ bhh0,
    const float* __restrict__ Wih1, const float* __restrict__ Whh1,
    const float* __restrict__ bih1, const float* __restrict__ bhh1,
    const float* __restrict__ fc1w, const float* __restrict__ fc1b,
    const float* __restrict__ fc2w, const float* __restrict__ fc2b,
    const float* __restrict__ fc3w, const float* __restrict__ fc3b,
    float* __restrict__ out)
{
    const int tid = threadIdx.x;
    const int wv  = tid >> 6;
    const int l   = tid & 63;
    const int l16 = l & 15;
    const int lg  = l >> 4;
    const int wg  = blockIdx.x;
    const int u   = wv * 16 + l16;

    __shared__ __align__(16) f16 hbuf[2][16 * HDIM];
    __shared__ float h2buf[16][HDIM];
    __shared__ float a1buf[16][64];
    __shared__ float a2buf[16][33];

    for (int i = tid; i < 16 * HDIM; i += 512) hbuf[0][i] = (f16)0.0f;

    float cst[4] = {0.f, 0.f, 0.f, 0.f};

    if (wg < N_PROD) {
        // ===================== PRODUCER: layer 0 =====================
        const int wgb = wg;
        f16x8 wih[4][3], whh[4][4];
        float biasv[4];
#pragma unroll
        for (int nt = 0; nt < 4; ++nt) {
            int gate = nt * 128 + u;
            biasv[nt] = bih0[gate] + bhh0[gate];
#pragma unroll
            for (int kc = 0; kc < 4; ++kc)
                whh[nt][kc] = load_wfrag(Whh0, gate, HDIM, kc * 32 + lg * 8, HDIM);
#pragma unroll
            for (int kc = 0; kc < 3; ++kc)
                wih[nt][kc] = load_wfrag(Wih0, gate, D_IN, kc * 32 + lg * 8, D_IN);
        }
        __syncthreads();

        // x rows are 80 f16 = 160B; kc=2 reads k=64..95, lanes lg>=2 read
        // garbage beyond the row -- harmless, their weight k-rows are zero.
        const f16* xrow = xT + (size_t)(wgb * B_TILE + l16) * T_SEQ * D_IN + lg * 8;
        uint64_t haddr = (uint64_t)(uintptr_t)h1ws +
                         (((uint64_t)wgb * B_TILE + lg * 4) * HDIM + u) * 2;
        int* myflags = flags + wgb * T_SEQ;

        f16x8 xc0 = *(const f16x8*)(xrow);
        f16x8 xc1 = *(const f16x8*)(xrow + 32);
        f16x8 xc2 = *(const f16x8*)(xrow + 64);

        for (int t = 0; t < T_SEQ; ++t) {
            int tn = (t < T_SEQ - 1) ? t + 1 : t;
            const f16* xp = xrow + tn * D_IN;
            f16x8 xn0 = *(const f16x8*)(xp);
            f16x8 xn1 = *(const f16x8*)(xp + 32);
            f16x8 xn2 = *(const f16x8*)(xp + 64);

            const f16* cur = hbuf[t & 1];
            f16* nxt = hbuf[(t + 1) & 1];
            f16x8 ha[4];
#pragma unroll
            for (int kc = 0; kc < 4; ++kc) {
                int chunk = kc * 4 + lg;
                ha[kc] = *(const f16x8*)(cur + l16 * HDIM + ((chunk ^ (l16 & 7)) << 3));
            }
            f32x4 acc[4];
#pragma unroll
            for (int nt = 0; nt < 4; ++nt) {
                f32x4 a = {biasv[nt], biasv[nt], biasv[nt], biasv[nt]};
                a = __builtin_amdgcn_mfma_f32_16x16x32_f16(xc0, wih[nt][0], a, 0, 0, 0);
                a = __builtin_amdgcn_mfma_f32_16x16x32_f16(xc1, wih[nt][1], a, 0, 0, 0);
                a = __builtin_amdgcn_mfma_f32_16x16x32_f16(xc2, wih[nt][2], a, 0, 0, 0);
                a = __builtin_amdgcn_mfma_f32_16x16x32_f16(ha[0], whh[nt][0], a, 0, 0, 0);
                a = __builtin_amdgcn_mfma_f32_16x16x32_f16(ha[1], whh[nt][1], a, 0, 0, 0);
                a = __builtin_amdgcn_mfma_f32_16x16x32_f16(ha[2], whh[nt][2], a, 0, 0, 0);
                a = __builtin_amdgcn_mfma_f32_16x16x32_f16(ha[3], whh[nt][3], a, 0, 0, 0);
                acc[nt] = a;
            }
            unsigned hv[4];
#pragma unroll
            for (int r = 0; r < 4; ++r) {
                float iv = sigm(acc[0][r]);
                float fv = sigm(acc[1][r]);
                float gv = tanh_fast(acc[2][r]);
                float ov = sigm(acc[3][r]);
                float cn = fv * cst[r] + iv * gv;
                cst[r] = cn;
                f16 hh = (f16)(ov * tanh_fast(cn));
                int br = lg * 4 + r;
                nxt[br * HDIM + ((((unsigned)u >> 3) ^ (br & 7)) << 3) + (u & 7)] = hh;
                hv[r] = (unsigned)__builtin_bit_cast(unsigned short, hh);
            }
            // h1[t][b][u] handoff rows (br = lg*4 + 0..3, row stride 256B)
            LLC_STORE_SHORT(haddr, hv[0], "0");
            LLC_STORE_SHORT(haddr, hv[1], "256");
            LLC_STORE_SHORT(haddr, hv[2], "512");
            LLC_STORE_SHORT(haddr, hv[3], "768");
            haddr += HSTEP_BYTES;
            xc0 = xn0; xc1 = xn1; xc2 = xn2;

            // drain handoff stores (+prefetch loads), then publish flag[t]
            asm volatile("s_waitcnt vmcnt(0) lgkmcnt(0)" ::: "memory");
            __builtin_amdgcn_sched_barrier(0);
            __builtin_amdgcn_s_barrier();
            __builtin_amdgcn_sched_barrier(0);
            if (tid == 0)
                __hip_atomic_store(&myflags[t], 1, __ATOMIC_RELAXED,
                                   __HIP_MEMORY_SCOPE_AGENT);
        }
        return;  // producers done
    }

    // ===================== CONSUMER: layer 1 + FC =====================
    {
        const int wgb = wg - N_PROD;
        f16x8 wih[4][4], whh[4][4];
        float biasv[4];
#pragma unroll
        for (int nt = 0; nt < 4; ++nt) {
            int gate = nt * 128 + u;
            biasv[nt] = bih1[gate] + bhh1[gate];
#pragma unroll
            for (int kc = 0; kc < 4; ++kc) {
                wih[nt][kc] = load_wfrag(Wih1, gate, HDIM, kc * 32 + lg * 8, HDIM);
                whh[nt][kc] = load_wfrag(Whh1, gate, HDIM, kc * 32 + lg * 8, HDIM);
            }
        }
        __syncthreads();  // hbuf zeros visible

        int* myflags = flags + wgb * T_SEQ;
        // wait for h1[0]
        if (tid == 0) { while (flag_ld(&myflags[0]) == 0) {} }
        __syncthreads();

        uint64_t xaddr = (uint64_t)(uintptr_t)h1ws +
                         ((uint64_t)(wgb * B_TILE + l16) * HDIM) * 2 + lg * 16;
        f16x8 xn0, xn1, xn2, xn3;
        LLC_LOAD(xn0, xaddr, "0");
        LLC_LOAD(xn1, xaddr, "64");
        LLC_LOAD(xn2, xaddr, "128");
        LLC_LOAD(xn3, xaddr, "192");

        float hlast[4] = {0.f, 0.f, 0.f, 0.f};

        for (int t = 0; t < T_SEQ; ++t) {
            asm volatile("s_waitcnt vmcnt(0)" ::: "memory");  // xn ready
            __builtin_amdgcn_sched_barrier(0);

            int probe = 1;
            if (t < T_SEQ - 1)
                probe = flag_ld(&myflags[t + 1]);  // latency hides under MFMA

            const f16* cur = hbuf[t & 1];
            f16* nxt = hbuf[(t + 1) & 1];
            f16x8 ha[4];
#pragma unroll
            for (int kc = 0; kc < 4; ++kc) {
                int chunk = kc * 4 + lg;
                ha[kc] = *(const f16x8*)(cur + l16 * HDIM + ((chunk ^ (l16 & 7)) << 3));
            }
            f32x4 acc[4];
#pragma unroll
            for (int nt = 0; nt < 4; ++nt) {
                f32x4 a = {biasv[nt], biasv[nt], biasv[nt], biasv[nt]};
                a = __builtin_amdgcn_mfma_f32_16x16x32_f16(xn0, wih[nt][0], a, 0, 0, 0);
                a = __builtin_amdgcn_mfma_f32_16x16x32_f16(xn1, wih[nt][1], a, 0, 0, 0);
                a = __builtin_amdgcn_mfma_f32_16x16x32_f16(xn2, wih[nt][2], a, 0, 0, 0);
                a = __builtin_amdgcn_mfma_f32_16x16x32_f16(xn3, wih[nt][3], a, 0, 0, 0);
                a = __builtin_amdgcn_mfma_f32_16x16x32_f16(ha[0], whh[nt][0], a, 0, 0, 0);
                a = __builtin_amdgcn_mfma_f32_16x16x32_f16(ha[1], whh[nt][1], a, 0, 0, 0);
                a = __builtin_amdgcn_mfma_f32_16x16x32_f16(ha[2], whh[nt][2], a, 0, 0, 0);
                a = __builtin_amdgcn_mfma_f32_16x16x32_f16(ha[3], whh[nt][3], a, 0, 0, 0);
                acc[nt] = a;
            }

            if (t < T_SEQ - 1) {
                if (!probe) { while (flag_ld(&myflags[t + 1]) == 0) {} }
                xaddr += HSTEP_BYTES;
                LLC_LOAD(xn0, xaddr, "0");
                LLC_LOAD(xn1, xaddr, "64");
                LLC_LOAD(xn2, xaddr, "128");
                LLC_LOAD(xn3, xaddr, "192");
            }

#pragma unroll
            for (int r = 0; r < 4; ++r) {
                float iv = sigm(acc[0][r]);
                float fv = sigm(acc[1][r]);
                float gv = tanh_fast(acc[2][r]);
                float ov = sigm(acc[3][r]);
                float cn = fv * cst[r] + iv * gv;
                cst[r] = cn;
                float hv = ov * tanh_fast(cn);
                hlast[r] = hv;
                int br = lg * 4 + r;
                nxt[br * HDIM + ((((unsigned)u >> 3) ^ (br & 7)) << 3) + (u & 7)] = (f16)hv;
            }
            wg_barrier_lds();
        }

        // ================= FC head on h2[:, T-1, :] =================
#pragma unroll
        for (int r = 0; r < 4; ++r) h2buf[lg * 4 + r][u] = hlast[r];
        __syncthreads();

        for (int i = tid; i < 16 * 64; i += 512) {
            int b = i >> 6, o = i & 63;
            float s = fc1b[o];
            for (int k = 0; k < HDIM; ++k) s += h2buf[b][k] * fc1w[o * HDIM + k];
            a1buf[b][o] = fmaxf(s, 0.f);
        }
        __syncthreads();
        if (tid < 16 * 32) {
            int b = tid >> 5, o = tid & 31;
            float s = fc2b[o];
            for (int k = 0; k < 64; ++k) s += a1buf[b][k] * fc2w[o * 64 + k];
            a2buf[b][o] = fmaxf(s, 0.f);
        }
        __syncthreads();
        if (tid < 32) {
            int b = tid >> 1, o = tid & 1;
            float s = fc3b[o];
            for (int k = 0; k < 32; ++k) s += a2buf[b][k] * fc3w[o * 32 + k];
            out[(wgb * B_TILE + b) * 2 + o] = s;
        }
    }
}

extern "C" void kernel_launch(void* const* d_in, const int* in_sizes, int n_in,
                              void* d_out, int out_size, void* d_ws, size_t ws_size,
                              hipStream_t stream)
{
    const float* x    = (const float*)d_in[0];
    const float* Wih0 = (const float*)d_in[1];
    const float* Whh0 = (const float*)d_in[2];
    const float* bih0 = (const float*)d_in[3];
    const float* bhh0 = (const float*)d_in[4];
    const float* Wih1 = (const float*)d_in[5];
    const float* Whh1 = (const float*)d_in[6];
    const float* bih1 = (const float*)d_in[7];
    const float* bhh1 = (const float*)d_in[8];
    const float* fc1w = (const float*)d_in[9];
    const float* fc1b = (const float*)d_in[10];
    const float* fc2w = (const float*)d_in[11];
    const float* fc2b = (const float*)d_in[12];
    const float* fc3w = (const float*)d_in[13];
    const float* fc3b = (const float*)d_in[14];

    f16* xT    = (f16*)d_ws;
    f16* h1    = (f16*)((char*)d_ws + XT_BYTES);
    int* flags = (int*)((char*)d_ws + FLAGS_OFF);

    // flags must be zero at the start of every launch (replays included)
    hipMemsetAsync(flags, 0, FLAGS_BYTES, stream);
    k_prep<<<B_ALL, 256, 0, stream>>>(x, xT);
    k_lstm<<<N_WG_TOT, 512, 0, stream>>>(xT, h1, flags, Wih0, Whh0, bih0, bhh0,
                                         Wih1, Whh1, bih1, bhh1,
                                         fc1w, fc1b, fc2w, fc2b, fc3w, fc3b,
                                         (float*)d_out);
}